// Round 4
// baseline (632.797 us; speedup 1.0000x reference)
//
#include <hip/hip_runtime.h>

// ---------------------------------------------------------------------------
// AttentionBlock: out = softmax((xWq^T)(xWk^T)^T / sqrt(512)) (xWv^T)
// R3: attn rewritten: swapped QK^T (S^T=K*Q) with permuted K-rows -> P is
//     lane-local in exact PV A-frag order (zero P/S LDS traffic); wave-pairs
//     split KV with independent online-softmax streams, merged at epilogue;
//     LDS = K+V tiles only (128KB); 4 raw barriers/iter, counted vmcnt(8).
// ---------------------------------------------------------------------------

typedef __bf16 bf16x8 __attribute__((ext_vector_type(8)));
typedef __bf16 bf16x4 __attribute__((ext_vector_type(4)));
typedef float  f32x4  __attribute__((ext_vector_type(4)));

constexpr int SEQ = 2048;
constexpr int DM  = 512;
constexpr int NB  = 8;
constexpr int GS  = NB * SEQ;    // 16384
constexpr int NT  = SEQ / 64;    // 32 kv tiles of 64 (pair-split 2x32)

__device__ __forceinline__ void gl16(const void* g, void* l) {
  __builtin_amdgcn_global_load_lds((const __attribute__((address_space(1))) void*)g,
                                   (__attribute__((address_space(3))) void*)l, 16, 0, 0);
}

__device__ __forceinline__ f32x4 mfma16(bf16x8 a, bf16x8 b, f32x4 c) {
  return __builtin_amdgcn_mfma_f32_16x16x32_bf16(a, b, c, 0, 0, 0);
}

// ---------------------------------------------------------------------------
// Kernel 0: fp32 -> bf16 conversion. Wq additionally scaled by log2(e)/sqrt(512)
// (folds the softmax scale + exp2 domain into Q).
// ---------------------------------------------------------------------------
__global__ void convert_kernel(const float* __restrict__ x,
                               const float* __restrict__ wq,
                               const float* __restrict__ wk,
                               const float* __restrict__ wv,
                               __bf16* __restrict__ xb,
                               __bf16* __restrict__ wqb,
                               __bf16* __restrict__ wkb,
                               __bf16* __restrict__ wvb) {
  const int NX4 = (GS * DM) / 4;
  const int NW4 = (DM * DM) / 4;
  const float SCL = 0.0637639022f;  // log2(e)/sqrt(512)
  const int stride = gridDim.x * blockDim.x;
  const int tid = blockIdx.x * blockDim.x + threadIdx.x;
  for (int i = tid; i < NX4; i += stride) {
    float4 v = ((const float4*)x)[i];
    bf16x4 o = { (__bf16)v.x, (__bf16)v.y, (__bf16)v.z, (__bf16)v.w };
    ((bf16x4*)xb)[i] = o;
  }
  for (int i = tid; i < NW4; i += stride) {
    float4 v = ((const float4*)wq)[i];
    bf16x4 o = { (__bf16)(v.x * SCL), (__bf16)(v.y * SCL),
                 (__bf16)(v.z * SCL), (__bf16)(v.w * SCL) };
    ((bf16x4*)wqb)[i] = o;
  }
  for (int i = tid; i < NW4; i += stride) {
    float4 v = ((const float4*)wk)[i];
    bf16x4 o = { (__bf16)v.x, (__bf16)v.y, (__bf16)v.z, (__bf16)v.w };
    ((bf16x4*)wkb)[i] = o;
  }
  for (int i = tid; i < NW4; i += stride) {
    float4 v = ((const float4*)wv)[i];
    bf16x4 o = { (__bf16)v.x, (__bf16)v.y, (__bf16)v.z, (__bf16)v.w };
    ((bf16x4*)wvb)[i] = o;
  }
}

// ---------------------------------------------------------------------------
// Kernel 1: NT GEMM  C[M][N] = A[M][512] * B[N][512]^T   (bf16 in, bf16 out)
// ---------------------------------------------------------------------------
__global__ __launch_bounds__(256, 2) void gemm_nt_kernel(
    const __bf16* __restrict__ A, const __bf16* __restrict__ Bm,
    __bf16* __restrict__ C, int N) {
  __shared__ __bf16 As[128 * 32];
  __shared__ __bf16 Bs[128 * 32];
  const int t = threadIdx.x;
  const int w = t >> 6, l = t & 63;
  const int l15 = l & 15, lg = l >> 4;
  const int m0 = blockIdx.x * 128, n0 = blockIdx.y * 128;
  const int wr = w >> 1, wc = w & 1;

  f32x4 acc[4][4] = {};
  const char* Ab = (const char*)A + (size_t)m0 * (DM * 2);
  const char* Bb = (const char*)Bm + (size_t)n0 * (DM * 2);

  for (int k0 = 0; k0 < DM; k0 += 32) {
#pragma unroll
    for (int i = 0; i < 2; ++i) {
      const int f = (i * 256 + t) * 16;
      const int row = f >> 6, c = f & 63;
      gl16(Ab + (size_t)row * (DM * 2) + k0 * 2 + c, (char*)As + f);
      gl16(Bb + (size_t)row * (DM * 2) + k0 * 2 + c, (char*)Bs + f);
    }
    __syncthreads();
    bf16x8 af[4], bfr[4];
#pragma unroll
    for (int mi = 0; mi < 4; ++mi)
      af[mi] = *(const bf16x8*)((const char*)As + (wr * 64 + mi * 16 + l15) * 64 + lg * 16);
#pragma unroll
    for (int ni = 0; ni < 4; ++ni)
      bfr[ni] = *(const bf16x8*)((const char*)Bs + (wc * 64 + ni * 16 + l15) * 64 + lg * 16);
#pragma unroll
    for (int mi = 0; mi < 4; ++mi)
#pragma unroll
      for (int ni = 0; ni < 4; ++ni)
        acc[mi][ni] = mfma16(af[mi], bfr[ni], acc[mi][ni]);
    __syncthreads();
  }
#pragma unroll
  for (int mi = 0; mi < 4; ++mi)
#pragma unroll
    for (int ni = 0; ni < 4; ++ni)
#pragma unroll
      for (int r = 0; r < 4; ++r) {
        const int row = m0 + wr * 64 + mi * 16 + lg * 4 + r;
        const int col = n0 + wc * 64 + ni * 16 + l15;
        C[(size_t)row * N + col] = (__bf16)acc[mi][ni][r];
      }
}

// ---------------------------------------------------------------------------
// Kernel 2: fused flash attention (R3).
// 256 blocks, 512 thr (8 waves). b=bid&7 (XCD-matched), q0=(bid>>3)*64.
// Wave w: pair=w>>1 owns q-rows [q0+pair*16, +16); wv=w&1 takes kv-half.
// Per iter (KVBLK=64): QK^T swapped (A=K permuted rows, B=Q regs) -> lane
// holds P[kv=wv*32+lg*8+j][q=l15] == PV A-frag; online softmax in-lane;
// PV: 32 e-frags, V from LDS. Epilogue: pair merge via LDS.
// LDS: Ks[64][512] (X_K=((r&3)<<1)|((r>>3)&1) chunk-xor), Vs[512][64]
// (slot^=(e&7)). 128KB, 1 blk/CU. vmcnt never drained to 0 in-loop.
// ---------------------------------------------------------------------------
__global__ __launch_bounds__(512, 2) void attn_kernel(
    const __bf16* __restrict__ QK, const __bf16* __restrict__ Vt,
    float* __restrict__ Out) {
  __shared__ __align__(16) __bf16 Ks[64 * 512];
  __shared__ __align__(16) __bf16 Vs[512 * 64];

  const int t = threadIdx.x;
  const int w = t >> 6, l = t & 63;
  const int l15 = l & 15, lg = l >> 4;
  const int b = blockIdx.x & 7;
  const int q0 = (blockIdx.x >> 3) * 64;
  const int pair = w >> 1;
  const int wv = w & 1;

  const char* QKc = (const char*)QK;
  const char* Vtc = (const char*)Vt;
  char* KsB = (char*)Ks;
  char* VsB = (char*)Vs;

  // ---- per-thread staging offsets ----
  // K: chunk l of row (i*8+w) holds global chunk l ^ X_K(row), X_K=((w&3)<<1)|(i&1)
  const int kcol = (l * 16) ^ ((w & 3) << 5);
  const size_t kbase = (size_t)(b * SEQ) * 2048 + 1024;  // K cols in fused QK
  // V: row e=i*64+(t>>3) (128B), slot (t&7) holds global slot (t&7)^(e&7)
  const int vrow = t >> 3;
  const int vcol = ((t & 7) * 16) ^ ((vrow & 7) << 4);
  const size_t vbase = (size_t)(b * SEQ) * 2;

  // ---- QK^T read constants ----
  // A-frag rows permuted: lane reads rows r0, r0+4 so that output reg r maps
  // to kv = wv*32 + lg*8 + r (S0) / +4+r (S1).
  const int r0 = wv * 32 + ((l15 & 12) << 1) + (l15 & 3);
  const int Xk = ((l15 & 3) << 1) | ((l15 >> 2) & 1);     // = X_K(r0) = X_K(r0+4)
  const int kb0 = r0 * 1024, kb1 = kb0 + 4096;
  // V read: addr = e*128 + voff + f*2048, e&7 == l15&7
  const int voff = (((lg + wv * 4) ^ (l15 & 7)) << 4) + l15 * 128;

  // ---- Q fragments (B-operand): rows q0+pair*16+l15, 16 kslices ----
  bf16x8 qf[16];
  {
    const char* Qp = QKc + (size_t)(b * SEQ + q0 + pair * 16 + l15) * 2048 + lg * 16;
#pragma unroll
    for (int ks = 0; ks < 16; ++ks)
      qf[ks] = *(const bf16x8*)(Qp + ks * 64);
  }

  // ---- stage tile 0 ----
#pragma unroll
  for (int i = 0; i < 8; ++i)
    gl16(QKc + kbase + (size_t)(i * 8 + w) * 2048 + (kcol ^ ((i & 1) << 4)),
         KsB + (i * 512 + t) * 16);
#pragma unroll
  for (int i = 0; i < 8; ++i)
    gl16(Vtc + vbase + (size_t)(i * 64 + vrow) * (GS * 2) + vcol,
         VsB + (i * 512 + t) * 16);

  asm volatile("s_waitcnt vmcnt(16)" ::: "memory");  // Q frags resident
  __builtin_amdgcn_sched_barrier(0);

  f32x4 o[32] = {};
  float m_run = -__builtin_inff(), l_run = 0.f;

  for (int it = 0; it < NT; ++it) {
    const int kvn = (it + 1 < NT ? it + 1 : 0) * 64;

    // ---- Ks[it] ready (K stage is oldest 8 of <=16 outstanding) ----
    asm volatile("s_waitcnt vmcnt(8)" ::: "memory");
    __builtin_amdgcn_sched_barrier(0);
    __builtin_amdgcn_s_barrier();

    // ---- QK^T: S^T = K~ * Q  (32 MFMA, K-rows permuted) ----
    f32x4 s0 = {}, s1 = {};
    __builtin_amdgcn_s_setprio(1);
#pragma unroll
    for (int ks = 0; ks < 16; ++ks) {
      const int c0 = ((ks * 4 + lg) ^ Xk) << 4;
      bf16x8 kf0 = *(const bf16x8*)(KsB + kb0 + c0);
      bf16x8 kf1 = *(const bf16x8*)(KsB + kb1 + c0);
      s0 = mfma16(kf0, qf[ks], s0);
      s1 = mfma16(kf1, qf[ks], s1);
    }
    __builtin_amdgcn_s_setprio(0);
    __builtin_amdgcn_s_barrier();   // all waves done reading Ks

    // ---- prefetch K[it+1] (lands by next top-of-loop wait) ----
#pragma unroll
    for (int i = 0; i < 8; ++i)
      gl16(QKc + kbase + (size_t)(kvn + i * 8 + w) * 2048 + (kcol ^ ((i & 1) << 4)),
           KsB + (i * 512 + t) * 16);

    // ---- online softmax, fully in-lane; p[j] <-> kv = wv*32+lg*8+j ----
    float p0 = s0[0], p1 = s0[1], p2 = s0[2], p3 = s0[3];
    float p4 = s1[0], p5 = s1[1], p6 = s1[2], p7 = s1[3];
    float tmax = fmaxf(fmaxf(fmaxf(p0, p1), fmaxf(p2, p3)),
                       fmaxf(fmaxf(p4, p5), fmaxf(p6, p7)));
    tmax = fmaxf(tmax, __shfl_xor(tmax, 16));
    tmax = fmaxf(tmax, __shfl_xor(tmax, 32));
    const float mnew = fmaxf(m_run, tmax);
    const float corr = exp2f(m_run - mnew);   // exactly 1.0f when no new max
    p0 = exp2f(p0 - mnew); p1 = exp2f(p1 - mnew);
    p2 = exp2f(p2 - mnew); p3 = exp2f(p3 - mnew);
    p4 = exp2f(p4 - mnew); p5 = exp2f(p5 - mnew);
    p6 = exp2f(p6 - mnew); p7 = exp2f(p7 - mnew);
    float rsum = ((p0 + p1) + (p2 + p3)) + ((p4 + p5) + (p6 + p7));
    rsum += __shfl_xor(rsum, 16);
    rsum += __shfl_xor(rsum, 32);
    l_run = l_run * corr + rsum;
    m_run = mnew;
    const bf16x8 pa = { (__bf16)p0, (__bf16)p1, (__bf16)p2, (__bf16)p3,
                        (__bf16)p4, (__bf16)p5, (__bf16)p6, (__bf16)p7 };

    // ---- rescale O on new max (wave-local decision) ----
    if (!__all(corr == 1.0f)) {
      float cr[4];
#pragma unroll
      for (int r = 0; r < 4; ++r) cr[r] = __shfl(corr, lg * 4 + r);
#pragma unroll
      for (int f = 0; f < 32; ++f)
#pragma unroll
        for (int r = 0; r < 4; ++r) o[f][r] *= cr[r];
    }

    // ---- Vs[it] ready ----
    asm volatile("s_waitcnt vmcnt(8)" ::: "memory");
    __builtin_amdgcn_sched_barrier(0);
    __builtin_amdgcn_s_barrier();

    // ---- PV: one in-reg A-frag vs 32 V-frags ----
    __builtin_amdgcn_s_setprio(1);
#pragma unroll
    for (int f = 0; f < 32; ++f) {
      bf16x8 vf = *(const bf16x8*)(VsB + f * 2048 + voff);
      o[f] = mfma16(pa, vf, o[f]);
    }
    __builtin_amdgcn_s_setprio(0);
    __builtin_amdgcn_s_barrier();   // all waves done reading Vs

    // ---- prefetch V[it+1] ----
#pragma unroll
    for (int i = 0; i < 8; ++i)
      gl16(Vtc + vbase + (size_t)kvn * 2 + (size_t)(i * 64 + vrow) * (GS * 2) + vcol,
           VsB + (i * 512 + t) * 16);
  }

  // ---- epilogue: drain, pair-merge (split-KV combine), normalize, store ----
  asm volatile("s_waitcnt vmcnt(0)" ::: "memory");
  __builtin_amdgcn_sched_barrier(0);
  __builtin_amdgcn_s_barrier();

  float* Sx = (float*)KsB;
  if (l < 16) {
    Sx[(pair * 2 + wv) * 32 + l15] = m_run;
    Sx[(pair * 2 + wv) * 32 + 16 + l15] = l_run;
  }
  __builtin_amdgcn_s_barrier();
  const float mP = Sx[(pair * 2 + (wv ^ 1)) * 32 + l15];
  const float lP = Sx[(pair * 2 + (wv ^ 1)) * 32 + 16 + l15];
  const float mst = fmaxf(m_run, mP);
  const float lst = l_run * exp2f(m_run - mst) + lP * exp2f(mP - mst);
  const float sc = exp2f(m_run - mst) / lst;   // self-weight / total
  __builtin_amdgcn_s_barrier();                // stats consumed; LDS reusable

  float cs[4];
#pragma unroll
  for (int r = 0; r < 4; ++r) cs[r] = __shfl(sc, lg * 4 + r);
#pragma unroll
  for (int f = 0; f < 32; ++f)
#pragma unroll
    for (int r = 0; r < 4; ++r) o[f][r] *= cs[r];

  float* R0 = (float*)KsB + pair * 4096;   // [16q][256e] e-half 0 (from wv=1)
  float* R1 = (float*)VsB + pair * 4096;   // e-half 1 (from wv=0)
  if (wv == 1) {
#pragma unroll
    for (int f = 0; f < 16; ++f)
#pragma unroll
      for (int r = 0; r < 4; ++r)
        R0[(lg * 4 + r) * 256 + f * 16 + l15] = o[f][r];
  } else {
#pragma unroll
    for (int f = 16; f < 32; ++f)
#pragma unroll
      for (int r = 0; r < 4; ++r)
        R1[(lg * 4 + r) * 256 + (f - 16) * 16 + l15] = o[f][r];
  }
  __builtin_amdgcn_s_barrier();

  float* Op = Out + ((size_t)b * SEQ + q0 + pair * 16) * DM;
  if (wv == 0) {
#pragma unroll
    for (int f = 0; f < 16; ++f)
#pragma unroll
      for (int r = 0; r < 4; ++r)
        Op[(lg * 4 + r) * DM + f * 16 + l15] =
            o[f][r] + R0[(lg * 4 + r) * 256 + f * 16 + l15];
  } else {
#pragma unroll
    for (int f = 16; f < 32; ++f)
#pragma unroll
      for (int r = 0; r < 4; ++r)
        Op[(lg * 4 + r) * DM + f * 16 + l15] =
            o[f][r] + R1[(lg * 4 + r) * 256 + (f - 16) * 16 + l15];
  }
}

// ---------------------------------------------------------------------------
// Launcher. Workspace (bytes, total 68,681,728):
//   xb 0 | wqkb 16777216 (Wq*SCL;Wk) | wvb 17825792 | qk 18350080
//   ([16384][1024]: Q cols 0..511, K cols 512..1023) | vt 51904512
// ---------------------------------------------------------------------------
extern "C" void kernel_launch(void* const* d_in, const int* in_sizes, int n_in,
                              void* d_out, int out_size, void* d_ws, size_t ws_size,
                              hipStream_t stream) {
  const float* x  = (const float*)d_in[0];
  const float* wq = (const float*)d_in[1];
  const float* wk = (const float*)d_in[2];
  const float* wv = (const float*)d_in[3];
  float* out = (float*)d_out;
  char* ws = (char*)d_ws;

  __bf16* xb   = (__bf16*)(ws);
  __bf16* wqkb = (__bf16*)(ws + 16777216);
  __bf16* wvb  = (__bf16*)(ws + 17825792);
  __bf16* qk   = (__bf16*)(ws + 18350080);
  __bf16* vt   = (__bf16*)(ws + 51904512);

  convert_kernel<<<2048, 256, 0, stream>>>(x, wq, wk, wv,
                                           xb, wqkb, wqkb + 262144, wvb);
  // [Q|K] = x * [Wq*SCL;Wk]^T : [16384x1024]
  gemm_nt_kernel<<<dim3(GS / 128, 1024 / 128), 256, 0, stream>>>(xb, wqkb, qk, 1024);
  // Vt[e][gs] = Wv * x^T : [512x16384]
  gemm_nt_kernel<<<dim3(DM / 128, GS / 128), 256, 0, stream>>>(wvb, xb, vt, GS);
  // fused attention
  attn_kernel<<<256, 512, 0, stream>>>(qk, vt, out);
}